// Round 2
// baseline (54.766 us; speedup 1.0000x reference)
//
#include <hip/hip_runtime.h>
#include <math.h>

#define DFEAT 50
#define NS 200                 // max series terms (reference uses 200)
#define BLOCK 256
#define ROWS_PER_BLOCK 256
#define F2_PER_ROW (DFEAT / 2)                         // 25
#define F4_PER_BLOCK (ROWS_PER_BLOCK * DFEAT / 4)      // 3200

// C = 25*ln(2*pi) - 24*ln(2)  (kappa-independent constant in -log_cmk)
#define CADD 29.311394326794948f
#define LN2F 0.6931471805599453f
#define LOG2E 1.4426950408889634f

__global__ __launch_bounds__(BLOCK) void nllvmf_kernel(const float* __restrict__ in,
                                                       float* __restrict__ out,
                                                       int rows, float inv_rows) {
    __shared__ float c2[NS];                       // (lgamma(j+1)+lgamma(j+25))*log2e
    __shared__ float tile[ROWS_PER_BLOCK * DFEAT]; // 50 KB row tile
    __shared__ float wsum[BLOCK / 64];

    const int tid = threadIdx.x;

    // Row-independent coefficient table (overlaps with staging).
    if (tid < NS) {
        float j = (float)tid;
        c2[tid] = (lgammaf(j + 1.0f) + lgammaf(j + 25.0f)) * LOG2E;
    }

    // ---- coalesced global -> LDS staging: 256 rows = 50 KB, float4 loads ----
    const int row0 = blockIdx.x * ROWS_PER_BLOCK;
    const size_t base = (size_t)row0 * DFEAT;
    const int nrow = min(ROWS_PER_BLOCK, rows - row0);
    const int nf4 = nrow * DFEAT / 4;              // DFEAT*nrow divisible by 2; full blocks by 4
    const float4* g4 = (const float4*)(in + base);
    float4* t4 = (float4*)tile;
    for (int i = tid; i < nf4; i += BLOCK)
        t4[i] = g4[i];
    __syncthreads();

    float v = 0.0f;
    if (tid < nrow) {
        // ---- kappa = L1 norm of my row, read from LDS ----
        const float2* myrow = (const float2*)tile + tid * F2_PER_ROW;
        float kappa = 0.0f;
#pragma unroll
        for (int i = 0; i < F2_PER_ROW; ++i) {
            float2 x = myrow[i];
            kappa += fabsf(x.x) + fabsf(x.y);
        }

        // ---- series in log2 space: t_j = j * (2*log2(kappa/2)) - c2[j] ----
        const float lx2 = 2.0f * log2f(kappa * 0.5f);

        // pass 1: running max with wave-uniform early exit (series is unimodal)
        float m = -1e30f;
        int jend = NS - 1;
        for (int j = 0; j < NS; ++j) {
            float t = fmaf((float)j, lx2, -c2[j]);
            m = fmaxf(m, t);
            if (__all(t < m - 30.0f)) { jend = j; break; }
        }

        // pass 2: sum exp2(t - m) over the significant range
        float s = 0.0f;
        for (int j = 0; j <= jend; ++j) {
            float t = fmaf((float)j, lx2, -c2[j]);
            s += exp2f(t - m);
        }

        // -log_cmk = ln(LSE) + C   (V*log(kappa) cancels to V*ln2, folded into C)
        v = fmaf(m + log2f(s), LN2F, CADD);
    }

    // ---- reduction: wave butterfly -> LDS -> one atomic per block ----
#pragma unroll
    for (int off = 32; off > 0; off >>= 1)
        v += __shfl_xor(v, off);

    const int wave = tid >> 6;
    if ((tid & 63) == 0) wsum[wave] = v;
    __syncthreads();

    if (tid == 0) {
        float b = 0.0f;
#pragma unroll
        for (int w = 0; w < BLOCK / 64; ++w) b += wsum[w];
        atomicAdd(out, b * inv_rows);
    }
}

extern "C" void kernel_launch(void* const* d_in, const int* in_sizes, int n_in,
                              void* d_out, int out_size, void* d_ws, size_t ws_size,
                              hipStream_t stream) {
    const float* in = (const float*)d_in[0];   // target (d_in[1]) is unused by the reference
    float* out = (float*)d_out;
    const int rows = in_sizes[0] / DFEAT;      // 524288

    hipMemsetAsync(d_out, 0, sizeof(float), stream);

    const int grid = (rows + ROWS_PER_BLOCK - 1) / ROWS_PER_BLOCK;
    nllvmf_kernel<<<grid, BLOCK, 0, stream>>>(in, out, rows, 1.0f / (float)rows);
}

// Round 3
// 43.317 us; speedup vs baseline: 1.2643x; 1.2643x over previous
//
#include <hip/hip_runtime.h>
#include <math.h>

#define DFEAT 50
#define NS 200          // coefficient table size (covers kappa up to ~300)
#define BLOCK 256
#define WIN 48          // series window: jpk-23 .. jpk+24

// C = 25*ln(2*pi) - 24*ln(2)  (kappa-independent constant in -log_cmk)
#define CADD 29.311394326794948f
#define LN2F 0.6931471805599453f
#define LOG2E 1.4426950408889634f

__global__ __launch_bounds__(BLOCK) void nllvmf_kernel(const float* __restrict__ in,
                                                       float* __restrict__ out,
                                                       int rows, float inv_rows) {
    __shared__ float c2[NS];            // (lgamma(j+1)+lgamma(j+25)) * log2(e)
    __shared__ float wsum[BLOCK / 64];

    const int tid = threadIdx.x;

    if (tid < NS) {
        float j = (float)tid;
        c2[tid] = (lgammaf(j + 1.0f) + lgammaf(j + 25.0f)) * LOG2E;
    }
    __syncthreads();

    const int row = blockIdx.x * BLOCK + tid;
    float v = 0.0f;

    if (row < rows) {
        // ---- kappa = L1 norm of my row (25 x float2; L1/L2/L3 absorb the stride) ----
        const float2* p = (const float2*)(in + (size_t)row * DFEAT);
        float kappa = 0.0f;
#pragma unroll
        for (int i = 0; i < DFEAT / 2; ++i) {
            float2 x = p[i];
            kappa += fabsf(x.x) + fabsf(x.y);
        }

        // ---- single-pass series around the analytic peak ----
        // t_j = j * 2*log2(kappa/2) - c2[j]; peak where (kappa/2)^2 = (j+1)(j+25)
        const float lx2 = 2.0f * log2f(kappa * 0.5f);
        const float q = 0.25f * kappa * kappa;
        int jpk = (int)(-13.0f + sqrtf(144.0f + q));
        if (jpk < 0) jpk = 0;
        int jlo = jpk - 23;
        if (jlo < 0) jlo = 0;

        // m = t(jpk): within ~0.5 log2 of the true integer max -> exp2 args <= ~1
        const float m = fmaf((float)jpk, lx2, -c2[jpk]);

        float s0 = 0.0f, s1 = 0.0f;
#pragma unroll
        for (int i = 0; i < WIN; i += 2) {
            int j0 = jlo + i;
            float t0 = fmaf((float)j0, lx2, -c2[j0]);
            float t1 = fmaf((float)(j0 + 1), lx2, -c2[j0 + 1]);
            s0 += exp2f(t0 - m);
            s1 += exp2f(t1 - m);
        }

        // -log_cmk = ln(LSE) + C   (V*log(kappa) cancels to V*ln2, folded into C)
        v = fmaf(m + log2f(s0 + s1), LN2F, CADD);
    }

    // ---- reduction: wave butterfly -> LDS -> one atomic per block ----
#pragma unroll
    for (int off = 32; off > 0; off >>= 1)
        v += __shfl_xor(v, off);

    const int wave = tid >> 6;
    if ((tid & 63) == 0) wsum[wave] = v;
    __syncthreads();

    if (tid == 0) {
        float b = 0.0f;
#pragma unroll
        for (int w = 0; w < BLOCK / 64; ++w) b += wsum[w];
        atomicAdd(out, b * inv_rows);
    }
}

extern "C" void kernel_launch(void* const* d_in, const int* in_sizes, int n_in,
                              void* d_out, int out_size, void* d_ws, size_t ws_size,
                              hipStream_t stream) {
    const float* in = (const float*)d_in[0];   // target (d_in[1]) is unused by the reference
    float* out = (float*)d_out;
    const int rows = in_sizes[0] / DFEAT;      // 524288

    hipMemsetAsync(d_out, 0, sizeof(float), stream);

    const int grid = (rows + BLOCK - 1) / BLOCK;
    nllvmf_kernel<<<grid, BLOCK, 0, stream>>>(in, out, rows, 1.0f / (float)rows);
}